// Round 1
// baseline (1166.129 us; speedup 1.0000x reference)
//
#include <hip/hip_runtime.h>
#include <hip/hip_bf16.h>

#define TT 4096
#define CC 3072
#define HH 24
#define DD 128

typedef __bf16 bf16;
typedef __attribute__((ext_vector_type(8))) __bf16 bf16x8;
typedef __attribute__((ext_vector_type(4))) __bf16 bf16x4;
typedef __attribute__((ext_vector_type(4))) float f32x4;

#define MFMA(a,b,c) __builtin_amdgcn_mfma_f32_16x16x32_bf16((a),(b),(c),0,0,0)

// ---------------- GEMM: C[M][N] = A[M][K] @ B[N][K]^T ----------------
// A: f32 (ABF=0) or bf16 (ABF=1), row-major [M][K]. B: f32 row-major [N][K].
// C: bf16 (OBF=1) or f32 (OBF=0), row-major [M][N].
template<int ABF, int OBF>
__global__ __launch_bounds__(256, 2)
void gemm_nt(const void* __restrict__ Ap, const float* __restrict__ Bp,
             void* __restrict__ Cp, int M, int N, int K) {
  __shared__ bf16 As[2][128][40];   // 32 K + 8 pad (80B row, 2-way bank alias = free)
  __shared__ bf16 Bs[2][128][40];
  const int tid = threadIdx.x;
  const int lane = tid & 63, wid = tid >> 6;
  const int m0 = blockIdx.y * 128, n0 = blockIdx.x * 128;
  const int wr = (wid >> 1) * 64, wc = (wid & 1) * 64;
  const int r = lane & 15, g = lane >> 4;
  const float* Af = (const float*)Ap;
  const bf16*  Ab = (const bf16*)Ap;

  f32x4 acc[4][4] = {};
  f32x4 pa[4], pb[4];
  bf16x8 qa[2];

  const int NT = K >> 5;

  auto load_tiles = [&](int kt) {
    const int kk = kt * 32;
    if constexpr (ABF) {
      #pragma unroll
      for (int j = 0; j < 2; ++j) {
        int c = tid + 256*j, row = c >> 2, kc = c & 3;
        qa[j] = *(const bf16x8*)(Ab + (size_t)(m0+row)*K + kk + kc*8);
      }
    } else {
      #pragma unroll
      for (int j = 0; j < 4; ++j) {
        int c = tid + 256*j, row = c >> 3, kc = c & 7;
        pa[j] = *(const f32x4*)(Af + (size_t)(m0+row)*K + kk + kc*4);
      }
    }
    #pragma unroll
    for (int j = 0; j < 4; ++j) {
      int c = tid + 256*j, row = c >> 3, kc = c & 7;
      pb[j] = *(const f32x4*)(Bp + (size_t)(n0+row)*K + kk + kc*4);
    }
  };

  auto write_tiles = [&](int buf) {
    if constexpr (ABF) {
      #pragma unroll
      for (int j = 0; j < 2; ++j) {
        int c = tid + 256*j, row = c >> 2, kc = c & 3;
        *(bf16x8*)&As[buf][row][kc*8] = qa[j];
      }
    } else {
      #pragma unroll
      for (int j = 0; j < 4; ++j) {
        int c = tid + 256*j, row = c >> 3, kc = c & 7;
        bf16x4 b;
        b[0]=(bf16)pa[j][0]; b[1]=(bf16)pa[j][1]; b[2]=(bf16)pa[j][2]; b[3]=(bf16)pa[j][3];
        *(bf16x4*)&As[buf][row][kc*4] = b;
      }
    }
    #pragma unroll
    for (int j = 0; j < 4; ++j) {
      int c = tid + 256*j, row = c >> 3, kc = c & 7;
      bf16x4 b;
      b[0]=(bf16)pb[j][0]; b[1]=(bf16)pb[j][1]; b[2]=(bf16)pb[j][2]; b[3]=(bf16)pb[j][3];
      *(bf16x4*)&Bs[buf][row][kc*4] = b;
    }
  };

  load_tiles(0);
  write_tiles(0);
  __syncthreads();

  for (int kt = 0; kt < NT; ++kt) {
    const int cur = kt & 1;
    if (kt + 1 < NT) load_tiles(kt + 1);      // issue next-tile global loads early
    bf16x8 af[4], bfr[4];
    #pragma unroll
    for (int m = 0; m < 4; ++m) af[m]  = *(const bf16x8*)&As[cur][wr + m*16 + r][g*8];
    #pragma unroll
    for (int n = 0; n < 4; ++n) bfr[n] = *(const bf16x8*)&Bs[cur][wc + n*16 + r][g*8];
    #pragma unroll
    for (int m = 0; m < 4; ++m)
      #pragma unroll
      for (int n = 0; n < 4; ++n)
        acc[m][n] = MFMA(af[m], bfr[n], acc[m][n]);
    if (kt + 1 < NT) write_tiles((kt + 1) & 1);  // write to the other buffer
    __syncthreads();
  }

  #pragma unroll
  for (int m = 0; m < 4; ++m)
    #pragma unroll
    for (int n = 0; n < 4; ++n) {
      const int col = n0 + wc + n*16 + r;
      #pragma unroll
      for (int j = 0; j < 4; ++j) {
        const int row = m0 + wr + m*16 + g*4 + j;
        float v = acc[m][n][j];
        if constexpr (OBF) ((bf16*)Cp)[(size_t)row*N + col] = (bf16)v;
        else               ((float*)Cp)[(size_t)row*N + col] = v;
      }
    }
}

// ---------------- RoPE (interleaved pairs), scale folded in ----------------
__global__ __launch_bounds__(256)
void rope_kernel(bf16* __restrict__ X, const float* __restrict__ F, float scale) {
  const int i = blockIdx.x * 256 + threadIdx.x;
  const size_t e8 = (size_t)i * 8;
  const int t  = (int)(e8 / CC);
  const int c  = (int)(e8 % CC);
  const int hc = c & (DD - 1);                    // offset within head (8-aligned)
  const float4* f = (const float4*)(F + (size_t)t*256 + (hc>>1)*4); // [cos,-sin,sin,cos]
  bf16x8 v = *(const bf16x8*)(X + e8);
  bf16x8 o;
  #pragma unroll
  for (int p = 0; p < 4; ++p) {
    float x0 = (float)v[2*p], x1 = (float)v[2*p+1];
    float4 ff = f[p];
    o[2*p]   = (bf16)((ff.x*x0 + ff.y*x1) * scale);
    o[2*p+1] = (bf16)((ff.z*x0 + ff.w*x1) * scale);
  }
  *(bf16x8*)(X + e8) = o;
}

// ---------------- V [T][C] -> Vt [H][D][T] per-head transpose ----------------
__global__ __launch_bounds__(256)
void transpose_v(const bf16* __restrict__ V, bf16* __restrict__ Vt) {
  __shared__ bf16 tile[64 * 128];                 // [t][d], XOR-swizzled
  const int t0 = blockIdx.x * 64, h = blockIdx.y;
  const int tid = threadIdx.x;
  #pragma unroll
  for (int j = 0; j < 4; ++j) {
    int c = tid + 256*j, t = c >> 4, c16 = c & 15;
    uint4 val = *(const uint4*)(V + (size_t)(t0+t)*CC + h*DD + c16*8);
    int sw = ((t & 7) ^ ((t >> 3) & 7)) << 4;
    *(uint4*)((char*)tile + t*256 + ((c16*16) ^ sw)) = val;
  }
  __syncthreads();
  #pragma unroll
  for (int j = 0; j < 4; ++j) {
    int c = tid + 256*j, d = c >> 3, c8 = c & 7;
    bf16x8 o;
    #pragma unroll
    for (int i = 0; i < 8; ++i) {
      int t = c8*8 + i;
      int sw = ((t & 7) ^ ((t >> 3) & 7)) << 4;
      o[i] = *(const bf16*)((char*)tile + t*256 + ((d*2) ^ sw));
    }
    *(bf16x8*)(Vt + (size_t)(h*DD + d)*TT + t0 + c8*8) = o;
  }
}

// ---------------- Flash attention: 1 block = (64 q-rows, 1 head) ----------------
// Q pre-scaled by 1/sqrt(D). K [T][C] bf16; Vt [H][D][T] bf16. O [T][C] bf16.
__global__ __launch_bounds__(256, 2)
void attn_kernel(const bf16* __restrict__ Q, const bf16* __restrict__ Kb,
                 const bf16* __restrict__ Vt, bf16* __restrict__ O) {
  __shared__ bf16 Ks[64 * 128];       // [kv][d], XOR-swizzled rows
  __shared__ bf16 Vs[128 * 64];       // [d][kv], XOR-swizzled rows
  __shared__ bf16 Ps[4][16 * 72];     // per-wave P [qrow][kv], 144B rows
  const int tid = threadIdx.x, lane = tid & 63, wid = tid >> 6;
  const int q0 = blockIdx.x * 64, h = blockIdx.y;
  const int r = lane & 15, g = lane >> 4;

  // Q fragments resident in registers (A-frag: row = lane&15, k = 8*(lane>>4)+e)
  bf16x8 aq[4];
  {
    const bf16* qp = Q + (size_t)(q0 + wid*16 + r)*CC + h*DD + g*8;
    #pragma unroll
    for (int kc = 0; kc < 4; ++kc) aq[kc] = *(const bf16x8*)(qp + kc*32);
  }

  float m_[4] = {-1e30f, -1e30f, -1e30f, -1e30f};
  float l_[4] = {0.f, 0.f, 0.f, 0.f};
  f32x4 o_[8] = {};
  char* PsW = (char*)&Ps[wid][0];

  for (int kv0 = 0; kv0 < TT; kv0 += 64) {
    __syncthreads();                               // prev compute done before restage
    #pragma unroll
    for (int j = 0; j < 4; ++j) {                  // stage K tile (64x128)
      int c = tid + 256*j, row = c >> 4, c16 = c & 15;
      uint4 val = *(const uint4*)(Kb + (size_t)(kv0+row)*CC + h*DD + c16*8);
      *(uint4*)((char*)Ks + row*256 + ((c16*16) ^ ((row & 7) << 4))) = val;
    }
    #pragma unroll
    for (int j = 0; j < 4; ++j) {                  // stage Vt tile (128x64)
      int c = tid + 256*j, row = c >> 3, c8 = c & 7;
      uint4 val = *(const uint4*)(Vt + (size_t)(h*DD+row)*TT + kv0 + c8*8);
      *(uint4*)((char*)Vs + row*128 + ((c8*16) ^ ((row & 7) << 4))) = val;
    }
    __syncthreads();

    // S = Q K^T  (wave: 16 q-rows x 64 kv-cols)
    f32x4 s[4] = {};
    #pragma unroll
    for (int kc = 0; kc < 4; ++kc)
      #pragma unroll
      for (int n = 0; n < 4; ++n) {
        int krow = n*16 + r;
        bf16x8 bk = *(const bf16x8*)((char*)Ks + krow*256 +
                                     ((kc*64 + g*16) ^ ((krow & 7) << 4)));
        s[n] = MFMA(aq[kc], bk, s[n]);
      }

    // online softmax; C-layout: col = lane&15, row = g*4+j
    float alpha[4], p[4][4];
    #pragma unroll
    for (int j = 0; j < 4; ++j) {
      float mx = fmaxf(fmaxf(s[0][j], s[1][j]), fmaxf(s[2][j], s[3][j]));
      #pragma unroll
      for (int st = 1; st < 16; st <<= 1) mx = fmaxf(mx, __shfl_xor(mx, st, 64));
      float mn = fmaxf(m_[j], mx);
      alpha[j] = __expf(m_[j] - mn);
      m_[j] = mn;
    }
    #pragma unroll
    for (int n = 0; n < 4; ++n)
      #pragma unroll
      for (int j = 0; j < 4; ++j) p[n][j] = __expf(s[n][j] - m_[j]);
    #pragma unroll
    for (int j = 0; j < 4; ++j) {
      float rs = p[0][j] + p[1][j] + p[2][j] + p[3][j];
      #pragma unroll
      for (int st = 1; st < 16; st <<= 1) rs += __shfl_xor(rs, st, 64);
      l_[j] = l_[j] * alpha[j] + rs;
    }
    #pragma unroll
    for (int t8 = 0; t8 < 8; ++t8)
      #pragma unroll
      for (int j = 0; j < 4; ++j) o_[t8][j] *= alpha[j];

    // P -> per-wave LDS (bf16), swizzled
    #pragma unroll
    for (int n = 0; n < 4; ++n)
      #pragma unroll
      for (int j = 0; j < 4; ++j) {
        int prow = g*4 + j;
        *(bf16*)(PsW + prow*144 + ((n*32 + r*2) ^ ((prow & 7) << 4))) = (bf16)p[n][j];
      }

    // O += P V   (A-frag from Ps, B-frag from Vs)
    #pragma unroll
    for (int kc2 = 0; kc2 < 2; ++kc2) {
      bf16x8 pa_ = *(const bf16x8*)(PsW + r*144 + ((kc2*64 + g*16) ^ ((r & 7) << 4)));
      #pragma unroll
      for (int t8 = 0; t8 < 8; ++t8) {
        int vrow = t8*16 + r;
        bf16x8 bv = *(const bf16x8*)((char*)Vs + vrow*128 +
                                     ((kc2*64 + g*16) ^ ((vrow & 7) << 4)));
        o_[t8] = MFMA(pa_, bv, o_[t8]);
      }
    }
  }

  #pragma unroll
  for (int t8 = 0; t8 < 8; ++t8)
    #pragma unroll
    for (int j = 0; j < 4; ++j) {
      int row = q0 + wid*16 + g*4 + j;
      int col = h*DD + t8*16 + r;
      O[(size_t)row*CC + col] = (bf16)(o_[t8][j] / l_[j]);
    }
}

// ---------------- host ----------------
extern "C" void kernel_launch(void* const* d_in, const int* in_sizes, int n_in,
                              void* d_out, int out_size, void* d_ws, size_t ws_size,
                              hipStream_t stream) {
  const float* x   = (const float*)d_in[0];
  const float* ctx = (const float*)d_in[1];
  const float* fr  = (const float*)d_in[2];
  const float* Wq  = (const float*)d_in[3];
  const float* Wk  = (const float*)d_in[4];
  const float* Wv  = (const float*)d_in[5];
  const float* Wo  = (const float*)d_in[6];
  float* out = (float*)d_out;
  char* ws = (char*)d_ws;

  const size_t SZ = (size_t)TT * CC * sizeof(bf16);   // 25,165,824 B
  bf16* Qb  = (bf16*)(ws);
  bf16* Kbf = (bf16*)(ws + SZ);
  bf16* Vb  = (bf16*)(ws + 2*SZ);
  bf16* Vtb = (bf16*)(ws + 3*SZ);
  bf16* Ob  = Vb;                                     // V reused after transpose

  dim3 gg(CC/128, TT/128);
  gemm_nt<0,1><<<gg, 256, 0, stream>>>(x,   Wq, Qb,  TT, CC, CC);
  gemm_nt<0,1><<<gg, 256, 0, stream>>>(ctx, Wk, Kbf, TT, CC, CC);
  gemm_nt<0,1><<<gg, 256, 0, stream>>>(ctx, Wv, Vb,  TT, CC, CC);

  const int rblocks = (TT*CC/8)/256;
  rope_kernel<<<rblocks, 256, 0, stream>>>(Qb,  fr, 0.08838834764831845f); // 1/sqrt(128)
  rope_kernel<<<rblocks, 256, 0, stream>>>(Kbf, fr, 1.0f);

  transpose_v<<<dim3(TT/64, HH), 256, 0, stream>>>(Vb, Vtb);
  attn_kernel<<<dim3(TT/64, HH), 256, 0, stream>>>(Qb, Kbf, Vtb, Ob);

  gemm_nt<1,0><<<gg, 256, 0, stream>>>(Ob, Wo, out, TT, CC, CC);
}